// Round 7
// baseline (57.934 us; speedup 1.0000x reference)
//
#include <hip/hip_runtime.h>
#include <math.h>

#define NB 256
#define NH 224
#define NW 224
#define HW (NH * NW)          // 50176
#define CHW (3 * HW)          // 150528
#define GP 4                  // pixels per thread
#define NT 256                // threads per block (4 waves)
#define WGR (NW / GP)         // 56 pixel-groups per row
#define GPI (HW / GP)         // 12544 groups per image
#define BPI (GPI / NT)        // 49 blocks per image

__global__ __launch_bounds__(NT) void aug_kernel(
    const int*   __restrict__ x,
    const float* __restrict__ flip_u, const float* __restrict__ bj_u,
    const float* __restrict__ cj_u,   const float* __restrict__ sj_u,
    const float* __restrict__ hue_u,  const float* __restrict__ erase_u,
    const float* __restrict__ area_u, const float* __restrict__ aspect_u,
    const float* __restrict__ top_u,  const float* __restrict__ left_u,
    const float* __restrict__ noise,  const float* __restrict__ mean,
    const float* __restrict__ stdv,
    float* __restrict__ out)
{
    // ---- 1) geometry from ids only -> x-loads issue with ZERO scalar deps ----
    const int bimg = blockIdx.x / BPI;
    const int r  = (blockIdx.x % BPI) * NT + threadIdx.x;  // 4-px group in image
    const int h  = r / WGR;
    const int w4 = (r - h * WGR) * GP;                     // SOURCE col of this thread
    const int base = bimg * CHW + h * NW;                  // fits in int32

    int4 xi0 = *(const int4*)(x + base          + w4);
    int4 xi1 = *(const int4*)(x + base + HW     + w4);
    int4 xi2 = *(const int4*)(x + base + 2*HW   + w4);

    // ---- 2) per-image params, overlapped with the in-flight loads ----
    // Flip is handled on the STORE side: this thread's pixels land at
    // dstw4 = NW-4-w4 in reversed order when flipped. Same cache lines per
    // wave -> coalescing preserved. Erase box evaluated in OUTPUT coords
    // (exactly where the reference applies it).
    const int flip = (flip_u[bimg] > 0.5f) ? 1 : 0;

    float b255, k1, k2;
    int apply, top, left, he, we;
    {
#pragma clang fp contract(off)
        // Erase-box integers MUST be bit-exact vs the fp32 reference ->
        // no FMA contraction, expression order mirrors the reference.
        float b_fac = 1.0f + (bj_u[bimg] * 2.0f - 1.0f) * 0.4f;
        float c_fac = 1.0f + (cj_u[bimg] * 2.0f - 1.0f) * 0.4f;
        float s_fac = 1.0f + (sj_u[bimg] * 2.0f - 1.0f) * 0.4f;
        float h_fac = (hue_u[bimg] * 2.0f - 1.0f) * 0.1f * 0.5f;
        float ang   = h_fac * 3.14159f;
        // contrast+saturation preserve the per-pixel mean -> whole color chain
        // collapses to: out_c = gray + k1*(c-gray) + k2*cross_c
        float cs = c_fac * s_fac;
        b255 = b_fac * (1.0f / 255.0f);
        k1   = cs * cosf(ang);
        k2   = cs * sinf(ang) * 0.5f;

        float ta     = (0.02f + area_u[bimg] * 0.31f) * (float)HW;
        float aspect = 0.3f + aspect_u[bimg] * 3.0f;
        he = (int)rintf(sqrtf(ta * aspect));   // jnp.round = half-even = rintf
        we = (int)rintf(sqrtf(ta / aspect));
        apply = (erase_u[bimg] < 0.25f) && (he < NH) && (we < NW);
        int th = NH - he + 1; if (th < 1) th = 1;
        int tw = NW - we + 1; if (tw < 1) tw = 1;
        top  = (int)floorf(top_u[bimg]  * (float)th);
        left = (int)floorf(left_u[bimg] * (float)tw);
    }

    const float i0 = 1.0f / stdv[0], i1 = 1.0f / stdv[1], i2 = 1.0f / stdv[2];
    const float mi0 = mean[0] * i0, mi1 = mean[1] * i1, mi2 = mean[2] * i2;
    const float third = 1.0f / 3.0f;

    // output position of this thread's group
    const int dstw4 = flip ? (NW - GP - w4) : w4;          // 16B-aligned

    // ---- 3) color transform (in source element order) ----
    float v[3][GP];
    {
        const int* p0 = (const int*)&xi0;
        const int* p1 = (const int*)&xi1;
        const int* p2 = (const int*)&xi2;
        #pragma unroll
        for (int i = 0; i < GP; ++i) {
            float r_ = (float)p0[i] * b255;       // brightness folded into /255
            float g_ = (float)p1[i] * b255;
            float b_ = (float)p2[i] * b255;

            float gray = (r_ + g_ + b_) * third;
            float rn = fmaf(k2, g_ - b_, fmaf(k1, r_ - gray, gray));
            float gn = fmaf(k2, b_ - r_, fmaf(k1, g_ - gray, gray));
            float bn = fmaf(k2, r_ - g_, fmaf(k1, b_ - gray, gray));

            rn = fminf(fmaxf(rn, 0.0f), 1.0f);    // v_med3
            gn = fminf(fmaxf(gn, 0.0f), 1.0f);
            bn = fminf(fmaxf(bn, 0.0f), 1.0f);

            // store slot: reversed order when flipped
            const int d = flip ? (GP - 1 - i) : i;
            v[0][d] = fmaf(rn, i0, -mi0);
            v[1][d] = fmaf(gn, i1, -mi1);
            v[2][d] = fmaf(bn, i2, -mi2);
        }
    }

    // ---- 4) random erase, in OUTPUT coordinates ----
    const bool rowin = apply && (h >= top) && (h < top + he);
    if (rowin) {
        #pragma unroll
        for (int i = 0; i < GP; ++i) {
            const int col = dstw4 + i;            // output column
            if (col >= left && col < left + we) {
                v[0][i] = noise[base          + col];
                v[1][i] = noise[base + HW     + col];
                v[2][i] = noise[base + 2*HW   + col];
            }
        }
    }

    // ---- 5) store at flipped position ----
    *(float4*)(out + base          + dstw4) = make_float4(v[0][0], v[0][1], v[0][2], v[0][3]);
    *(float4*)(out + base + HW     + dstw4) = make_float4(v[1][0], v[1][1], v[1][2], v[1][3]);
    *(float4*)(out + base + 2*HW   + dstw4) = make_float4(v[2][0], v[2][1], v[2][2], v[2][3]);
}

extern "C" void kernel_launch(void* const* d_in, const int* in_sizes, int n_in,
                              void* d_out, int out_size, void* d_ws, size_t ws_size,
                              hipStream_t stream) {
    const int*   x        = (const int*)  d_in[0];
    const float* flip_u   = (const float*)d_in[1];
    const float* bj_u     = (const float*)d_in[2];
    const float* cj_u     = (const float*)d_in[3];
    const float* sj_u     = (const float*)d_in[4];
    const float* hue_u    = (const float*)d_in[5];
    const float* erase_u  = (const float*)d_in[6];
    const float* area_u   = (const float*)d_in[7];
    const float* aspect_u = (const float*)d_in[8];
    const float* top_u    = (const float*)d_in[9];
    const float* left_u   = (const float*)d_in[10];
    const float* noise    = (const float*)d_in[11];
    const float* mean     = (const float*)d_in[12];
    const float* stdv     = (const float*)d_in[13];
    float* out = (float*)d_out;

    const int grid = NB * BPI;   // 256 images * 49 blocks = 12544
    aug_kernel<<<grid, NT, 0, stream>>>(x, flip_u, bj_u, cj_u, sj_u, hue_u,
                                        erase_u, area_u, aspect_u, top_u, left_u,
                                        noise, mean, stdv, out);
}